// Round 3
// baseline (255.547 us; speedup 1.0000x reference)
//
#include <hip/hip_runtime.h>
#include <stdint.h>

// B=8, OBJ=128, INP=64, HID=256, D=192.
// R24: occupancy ladder, take 3. R22 (cap 128, 256thr) and R23 (cap 128,
// 512thr) both spilled: with AGPRs live the allocator splits 64 arch + 64
// acc and spills arch demand above 64 (WRITE_SIZE 133MB / 64MB). Fix: ask
// for 3 waves/SIMD (launch_bounds(256,3), cap ~168): acc 64 AGPR + af
// ring-4 32 + bfr 16 + temps ~30 = ~145 unified, 20+ regs slack -> no
// spill. Two-pass j-split keeps hbuf 32KB (+1KB ms): 3 blocks/CU = 37.5%
// occupancy vs R20's 20.7%. Same math/swizzle/epilogue as R20 otherwise.
// Setup kernel byte-identical.

#define HID 256
#define NOBJ 128
#define NROW 1024   // B*OBJ

typedef __attribute__((ext_vector_type(8))) short short8;
typedef __attribute__((ext_vector_type(4))) float float4v;
typedef __attribute__((ext_vector_type(16))) float float16v;
typedef __attribute__((ext_vector_type(2))) unsigned int uint2v;

__device__ __forceinline__ unsigned int f2bf_u(float f) {
    unsigned int u = __builtin_bit_cast(unsigned int, f);
    u += 0x7fffu + ((u >> 16) & 1u);   // RNE
    return u >> 16;
}
__device__ __forceinline__ unsigned int pack2(float a, float b) {
    return f2bf_u(a) | (f2bf_u(b) << 16);
}
__device__ __forceinline__ float relu(float v) { return v > 0.f ? v : 0.f; }

// LDS-only barrier: leaves global-load (vmcnt) prefetches in flight.
__device__ __forceinline__ void lds_barrier() {
    asm volatile("s_waitcnt lgkmcnt(0)\n\ts_barrier" ::: "memory");
}

// ---- setup:
//  blocks [0,16): fragment-major pack of w1,w2 (layer m = bx>>3, n-tile tau = bx&7)
//  blocks [16,528): encoder, 2 rows each (fold b_enc into ea)
//  blocks [528,784): W34 row m = bx-528:  W34[m][o] = sum_k w3[m][k]*wd1[k][o]
//  block  784:       b34[o] = sum_k b3[k]*wd1[k][o] + bd1[o]
__global__ void setup_kernel(const float* __restrict__ x0, const float* __restrict__ x1,
                             const float* __restrict__ x2, const float* __restrict__ w_enc,
                             const float* __restrict__ b_enc,
                             const float* __restrict__ w1, const float* __restrict__ w2,
                             const float* __restrict__ w3, const float* __restrict__ b3,
                             const float* __restrict__ wd1, const float* __restrict__ bd1,
                             unsigned short* __restrict__ wt,
                             float* __restrict__ ea, float* __restrict__ eb,
                             float* __restrict__ W34, float* __restrict__ b34) {
    const int bx = blockIdx.x, t = threadIdx.x;
    __shared__ float lw[256][33];          // [k][n-within-tile]
    __shared__ float xs[2][192];
    if (bx < 16) {
        const int m = bx >> 3, tau = bx & 7;
        const float* w = (m == 0) ? w1 : w2;
        const int n = t & 31, kk = t >> 5;     // 8 k-rows per pass
#pragma unroll
        for (int rep = 0; rep < 32; ++rep) {
            int k = rep * 8 + kk;
            lw[k][n] = w[k * 256 + tau * 32 + n];   // coalesced 128B segments
        }
        __syncthreads();
        unsigned short* outp = wt + (m * 8 + tau) * 8192;
        const int lane = t & 63, wq = t >> 6;
        const int h5 = lane >> 5, l31n = lane & 31;
#pragma unroll
        for (int rep = 0; rep < 4; ++rep) {
            const int kb = wq * 4 + rep;
            short8 v;
#pragma unroll
            for (int e = 0; e < 8; ++e)
                v[e] = (short)f2bf_u(lw[kb * 16 + h5 * 8 + e][l31n]);
            *(short8*)(outp + kb * 512 + lane * 8) = v;   // wave-contiguous 1KB
        }
        return;
    }
    if (bx < 528) {
        const int e = bx - 16;                 // 512 groups x 2 rows
        for (int idx = t; idx < 384; idx += 256) {
            int r = idx / 192, d = idx % 192;
            int row = e * 2 + r;
            float v = (d < 64) ? x0[row * 64 + d]
                    : (d < 128) ? x1[row * 64 + d - 64]
                    : x2[row * 64 + d - 128];
            xs[r][d] = v;
        }
        __syncthreads();
        float aA[2] = {0.f, 0.f}, aB[2] = {0.f, 0.f};
#pragma unroll 16
        for (int d = 0; d < 192; ++d) {
            float wa = w_enc[d * 256 + t];
            float wb = w_enc[(192 + d) * 256 + t];
#pragma unroll
            for (int r = 0; r < 2; ++r) { aA[r] += xs[r][d] * wa; aB[r] += xs[r][d] * wb; }
        }
        float be = b_enc[t];
#pragma unroll
        for (int r = 0; r < 2; ++r) {
            ea[(e * 2 + r) * 256 + t] = aA[r] + be;
            eb[(e * 2 + r) * 256 + t] = aB[r];
        }
        return;
    }
    if (bx < 784) {
        const int m = bx - 528;
        float a = 0.f;
#pragma unroll 8
        for (int k = 0; k < 256; ++k) a += w3[m * 256 + k] * wd1[k * 256 + t];
        W34[m * 256 + t] = a;
        return;
    }
    {   // b34
        float a = bd1[t];
#pragma unroll 8
        for (int k = 0; k < 256; ++k) a += b3[k] * wd1[k * 256 + t];
        b34[t] = a;
    }
}

// ---- pair MLP (2 layers) + fused decoder: grid 1024, one WG (256 thr) per (b,i).
//      j processed in TWO 64-row passes; 32KB LDS h + 1KB pooled accumulator.
//      swizzle: elem(j,k) at j*256 + ((k>>3 ^ (j&31))<<3) + (k&7).
//      Wave wv owns n-slice n0=wv*64 as tn=2 x tj=2 tiles of 32x32x16.
//      af ring-4 (prefetch distance 3), bfr double-buffered.
__global__ __launch_bounds__(256, 3) void pair_kernel(
        const float* __restrict__ ea, const float* __restrict__ eb,
        const unsigned short* __restrict__ wt,
        const float* __restrict__ b1, const float* __restrict__ b2,
        const float* __restrict__ W34, const float* __restrict__ b34,
        const float* __restrict__ wd2, const float* __restrict__ bd2,
        float* __restrict__ out) {
    __shared__ __align__(16) unsigned short hbuf[64 * 256];   // 32 KB
    __shared__ float ms[HID];   // pooled (sum over j) accumulator, per-n

    const int w = blockIdx.x, b = w >> 7;
    const int t = threadIdx.x, wv = t >> 6, lane = t & 63;
    const int l31 = lane & 31, h5 = lane >> 5;
    const int n0 = wv * 64;

    const unsigned short* aptr = wt + lane * 8;   // + ((l*8 + wv*2+tn)*16 + kb)*512

    short8 af[4][2], bfr[2][2];
    float16v acc[2][2];   // [tn][tj]

#pragma unroll 1
    for (int pass = 0; pass < 2; ++pass) {
        // ring-4 preload: steps g = 0,1,2 of layer 0 (latency hides under preamble)
#pragma unroll
        for (int pg = 0; pg < 3; ++pg) {
            af[pg][0] = *(const short8*)(aptr + ((wv * 2 + 0) * 16 + pg) * 512);
            af[pg][1] = *(const short8*)(aptr + ((wv * 2 + 1) * 16 + pg) * 512);
        }

        // preamble: h0[j][k] = relu(ea[w][k] + eb[b*128 + pass*64 + j][k])
        // wave fills rows j = wv*16 .. wv*16+15 (j is LOCAL to this pass)
        {
            const float4v va = *(const float4v*)(ea + w * 256 + lane * 4);
            const float* ebbase = eb + (b * NOBJ + pass * 64) * 256;
            const int c = lane >> 1, sub = (lane & 1) * 4;
#pragma unroll 4
            for (int jj = 0; jj < 16; ++jj) {
                const int j = wv * 16 + jj;
                float4v vb = *(const float4v*)(ebbase + j * 256 + lane * 4);
                int addr = j * 256 + ((c ^ (j & 31)) << 3) + sub;
                *(uint2v*)(hbuf + addr) = (uint2v){
                    pack2(relu(va[0] + vb[0]), relu(va[1] + vb[1])),
                    pack2(relu(va[2] + vb[2]), relu(va[3] + vb[3]))};
            }
        }
        lds_barrier();

        int jb[2];
#pragma unroll
        for (int tj = 0; tj < 2; ++tj) jb[tj] = (tj * 32 + l31) * 256;
#pragma unroll
        for (int tj = 0; tj < 2; ++tj)
            bfr[0][tj] = *(const short8*)(hbuf + jb[tj] + ((h5 ^ l31) << 3));

#pragma unroll
        for (int l = 0; l < 2; ++l) {
            const float* bias = (l == 0) ? b1 : b2;
#pragma unroll
            for (int tn = 0; tn < 2; ++tn)
#pragma unroll
                for (int q = 0; q < 4; ++q) {
                    float4v bv = *(const float4v*)(bias + n0 + tn * 32 + q * 8 + h5 * 4);
#pragma unroll
                    for (int i = 0; i < 4; ++i)
#pragma unroll
                        for (int tj = 0; tj < 2; ++tj)
                            acc[tn][tj][q * 4 + i] = bv[i];
                }
#pragma unroll
            for (int kb = 0; kb < 16; ++kb) {
                const int g = l * 16 + kb, gp = g + 3;
                if (gp < 32) {   // ring-4: prefetch 3 steps ahead (crosses layers)
                    const int lp = gp >> 4, kp = gp & 15;
                    af[gp & 3][0] = *(const short8*)(aptr + ((lp * 8 + wv * 2 + 0) * 16 + kp) * 512);
                    af[gp & 3][1] = *(const short8*)(aptr + ((lp * 8 + wv * 2 + 1) * 16 + kp) * 512);
                }
                if (kb < 15) {   // prefetch next step's B from LDS
                    const int off = ((((kb + 1) * 2 + h5) ^ l31) << 3);
#pragma unroll
                    for (int tj = 0; tj < 2; ++tj)
                        bfr[(kb + 1) & 1][tj] = *(const short8*)(hbuf + jb[tj] + off);
                }
#pragma unroll
                for (int tn = 0; tn < 2; ++tn)
#pragma unroll
                    for (int tj = 0; tj < 2; ++tj)
                        acc[tn][tj] = __builtin_amdgcn_mfma_f32_32x32x16_bf16(
                            af[g & 3][tn], bfr[kb & 1][tj], acc[tn][tj], 0, 0, 0);
            }
            lds_barrier();   // hbuf reads of layer l done

            if (l == 0) {
                // writeback h1 (relu, bf16) into swizzled layout
#pragma unroll
                for (int tn = 0; tn < 2; ++tn)
#pragma unroll
                    for (int q = 0; q < 4; ++q) {
                        const int nb_ = n0 + tn * 32 + 8 * q + 4 * h5;
                        const int cn = nb_ >> 3, sub = nb_ & 7;
#pragma unroll
                        for (int tj = 0; tj < 2; ++tj) {
                            const int j = tj * 32 + l31;
                            int addr = j * 256 + ((cn ^ l31) << 3) + sub;
                            *(uint2v*)(hbuf + addr) = (uint2v){
                                pack2(relu(acc[tn][tj][q * 4]), relu(acc[tn][tj][q * 4 + 1])),
                                pack2(relu(acc[tn][tj][q * 4 + 2]), relu(acc[tn][tj][q * 4 + 3]))};
                        }
                    }
                lds_barrier();
#pragma unroll
                for (int tj = 0; tj < 2; ++tj)
                    bfr[0][tj] = *(const short8*)(hbuf + jb[tj] + ((h5 ^ l31) << 3));
            }
        }

        // partial pooled sum over this pass's 64 j rows:
        // col j = l31, row n = n0 + tn*32 + (r&3) + 8*(r>>2) + 4*h5
#pragma unroll
        for (int tn = 0; tn < 2; ++tn)
#pragma unroll
            for (int r = 0; r < 16; ++r) {
                float s = relu(acc[tn][0][r]) + relu(acc[tn][1][r]);
                s += __shfl_xor(s, 1);
                s += __shfl_xor(s, 2);
                s += __shfl_xor(s, 4);
                s += __shfl_xor(s, 8);
                s += __shfl_xor(s, 16);
                if (l31 == 0) {
                    const int n = n0 + tn * 32 + (r & 3) + 8 * (r >> 2) + 4 * h5;
                    if (pass == 0) ms[n] = s;
                    else           ms[n] = (ms[n] + s) * 0.0078125f;   // /128
                }
            }
    }
    __syncthreads();

    // ---- epilogue: t1 = relu(m2@W34 + b34); out = t1@wd2 + bd2
    // fs aliases hbuf (all h reads done): p1[0..1024) | t1[1024..1280) | p2[1280..1536)
    float* fs = (float*)hbuf;
    {   // stage 1: m2 @ W34, 4-way k-split (wave wv covers k in [wv*64, wv*64+64))
        float p0 = 0.f, p1 = 0.f, p2 = 0.f, p3 = 0.f;
        const float* wp = W34 + (wv * 64) * 256 + lane;
#pragma unroll 8
        for (int kk = 0; kk < 64; ++kk) {
            float mv = ms[wv * 64 + kk];
            p0 += mv * wp[kk * 256];
            p1 += mv * wp[kk * 256 + 64];
            p2 += mv * wp[kk * 256 + 128];
            p3 += mv * wp[kk * 256 + 192];
        }
        fs[wv * 256 + lane]       = p0;
        fs[wv * 256 + 64 + lane]  = p1;
        fs[wv * 256 + 128 + lane] = p2;
        fs[wv * 256 + 192 + lane] = p3;
    }
    __syncthreads();
    fs[1024 + t] = relu(fs[t] + fs[256 + t] + fs[512 + t] + fs[768 + t] + b34[t]);
    __syncthreads();
    {   // stage 2: t1 @ wd2 (wave wv covers k in [wv*64, wv*64+64), lane = output o)
        float p = 0.f;
        const float* w2p = wd2 + (wv * 64) * 64 + lane;
#pragma unroll 8
        for (int kk = 0; kk < 64; ++kk) p += fs[1024 + wv * 64 + kk] * w2p[kk * 64];
        fs[1280 + wv * 64 + lane] = p;
    }
    __syncthreads();
    if (t < 64)
        out[w * 64 + t] = fs[1280 + t] + fs[1344 + t] + fs[1408 + t] + fs[1472 + t] + bd2[t];
}

extern "C" void kernel_launch(void* const* d_in, const int* in_sizes, int n_in,
                              void* d_out, int out_size, void* d_ws, size_t ws_size,
                              hipStream_t stream) {
    const float* x0    = (const float*)d_in[0];
    const float* x1    = (const float*)d_in[1];
    const float* x2    = (const float*)d_in[2];
    const float* w_enc = (const float*)d_in[3];
    const float* b_enc = (const float*)d_in[4];
    const float* w1    = (const float*)d_in[5];
    const float* b1    = (const float*)d_in[6];
    const float* w2    = (const float*)d_in[7];
    const float* b2    = (const float*)d_in[8];
    const float* w3    = (const float*)d_in[9];
    const float* b3    = (const float*)d_in[10];
    const float* wd1   = (const float*)d_in[11];
    const float* bd1   = (const float*)d_in[12];
    const float* wd2   = (const float*)d_in[13];
    const float* bd2   = (const float*)d_in[14];
    float* out = (float*)d_out;

    // workspace: wfrag 256KB (in 384KB slot) | ea 1MB | eb 1MB | W34 256KB | b34 1KB
    unsigned short* wt = (unsigned short*)d_ws;
    float* ea  = (float*)((char*)d_ws + 3 * 65536 * sizeof(unsigned short));
    float* eb  = ea + NROW * HID;
    float* W34 = eb + NROW * HID;
    float* b34 = W34 + 256 * 256;

    setup_kernel<<<785, 256, 0, stream>>>(x0, x1, x2, w_enc, b_enc, w1, w2,
                                          w3, b3, wd1, bd1, wt, ea, eb, W34, b34);
    pair_kernel<<<NROW, 256, 0, stream>>>(ea, eb, wt, b1, b2, W34, b34, wd2, bd2, out);
}

// Round 4
// 195.111 us; speedup vs baseline: 1.3098x; 1.3098x over previous
//
#include <hip/hip_runtime.h>
#include <stdint.h>

// B=8, OBJ=128, INP=64, HID=256, D=192.
// R25: two-row blocks in the proven no-spill regime. R22/R23/R24 showed any
// launch_bounds tighter than (256,2) spills with big AGPR accs (WRITE_SIZE
// 270/64/225 MB). So keep (256,2) / 228-reg shape and instead DOUBLE MFMA
// issue density per wave: each block handles rows w0=2bx, w0+1 (same b);
// per k-step 16 independent MFMAs (512 cyc) -> matrix pipe saturated during
// K-loops at 2 waves/SIMD. af ring shared across rows (wt traffic halves),
// eb preamble load shared (1 load -> 2 stores). Two-pass j-split: hbuf
// 2x32KB + ms 2KB = 66KB -> 2 blocks/CU; grid 512 = 256CUx2 -> single
// round, all blocks resident. Setup kernel byte-identical.

#define HID 256
#define NOBJ 128
#define NROW 1024   // B*OBJ

typedef __attribute__((ext_vector_type(8))) short short8;
typedef __attribute__((ext_vector_type(4))) float float4v;
typedef __attribute__((ext_vector_type(16))) float float16v;
typedef __attribute__((ext_vector_type(2))) unsigned int uint2v;

__device__ __forceinline__ unsigned int f2bf_u(float f) {
    unsigned int u = __builtin_bit_cast(unsigned int, f);
    u += 0x7fffu + ((u >> 16) & 1u);   // RNE
    return u >> 16;
}
__device__ __forceinline__ unsigned int pack2(float a, float b) {
    return f2bf_u(a) | (f2bf_u(b) << 16);
}
__device__ __forceinline__ float relu(float v) { return v > 0.f ? v : 0.f; }

// LDS-only barrier: leaves global-load (vmcnt) prefetches in flight.
__device__ __forceinline__ void lds_barrier() {
    asm volatile("s_waitcnt lgkmcnt(0)\n\ts_barrier" ::: "memory");
}

// ---- setup:
//  blocks [0,16): fragment-major pack of w1,w2 (layer m = bx>>3, n-tile tau = bx&7)
//  blocks [16,528): encoder, 2 rows each (fold b_enc into ea)
//  blocks [528,784): W34 row m = bx-528:  W34[m][o] = sum_k w3[m][k]*wd1[k][o]
//  block  784:       b34[o] = sum_k b3[k]*wd1[k][o] + bd1[o]
__global__ void setup_kernel(const float* __restrict__ x0, const float* __restrict__ x1,
                             const float* __restrict__ x2, const float* __restrict__ w_enc,
                             const float* __restrict__ b_enc,
                             const float* __restrict__ w1, const float* __restrict__ w2,
                             const float* __restrict__ w3, const float* __restrict__ b3,
                             const float* __restrict__ wd1, const float* __restrict__ bd1,
                             unsigned short* __restrict__ wt,
                             float* __restrict__ ea, float* __restrict__ eb,
                             float* __restrict__ W34, float* __restrict__ b34) {
    const int bx = blockIdx.x, t = threadIdx.x;
    __shared__ float lw[256][33];          // [k][n-within-tile]
    __shared__ float xs[2][192];
    if (bx < 16) {
        const int m = bx >> 3, tau = bx & 7;
        const float* w = (m == 0) ? w1 : w2;
        const int n = t & 31, kk = t >> 5;     // 8 k-rows per pass
#pragma unroll
        for (int rep = 0; rep < 32; ++rep) {
            int k = rep * 8 + kk;
            lw[k][n] = w[k * 256 + tau * 32 + n];   // coalesced 128B segments
        }
        __syncthreads();
        unsigned short* outp = wt + (m * 8 + tau) * 8192;
        const int lane = t & 63, wq = t >> 6;
        const int h5 = lane >> 5, l31n = lane & 31;
#pragma unroll
        for (int rep = 0; rep < 4; ++rep) {
            const int kb = wq * 4 + rep;
            short8 v;
#pragma unroll
            for (int e = 0; e < 8; ++e)
                v[e] = (short)f2bf_u(lw[kb * 16 + h5 * 8 + e][l31n]);
            *(short8*)(outp + kb * 512 + lane * 8) = v;   // wave-contiguous 1KB
        }
        return;
    }
    if (bx < 528) {
        const int e = bx - 16;                 // 512 groups x 2 rows
        for (int idx = t; idx < 384; idx += 256) {
            int r = idx / 192, d = idx % 192;
            int row = e * 2 + r;
            float v = (d < 64) ? x0[row * 64 + d]
                    : (d < 128) ? x1[row * 64 + d - 64]
                    : x2[row * 64 + d - 128];
            xs[r][d] = v;
        }
        __syncthreads();
        float aA[2] = {0.f, 0.f}, aB[2] = {0.f, 0.f};
#pragma unroll 16
        for (int d = 0; d < 192; ++d) {
            float wa = w_enc[d * 256 + t];
            float wb = w_enc[(192 + d) * 256 + t];
#pragma unroll
            for (int r = 0; r < 2; ++r) { aA[r] += xs[r][d] * wa; aB[r] += xs[r][d] * wb; }
        }
        float be = b_enc[t];
#pragma unroll
        for (int r = 0; r < 2; ++r) {
            ea[(e * 2 + r) * 256 + t] = aA[r] + be;
            eb[(e * 2 + r) * 256 + t] = aB[r];
        }
        return;
    }
    if (bx < 784) {
        const int m = bx - 528;
        float a = 0.f;
#pragma unroll 8
        for (int k = 0; k < 256; ++k) a += w3[m * 256 + k] * wd1[k * 256 + t];
        W34[m * 256 + t] = a;
        return;
    }
    {   // b34
        float a = bd1[t];
#pragma unroll 8
        for (int k = 0; k < 256; ++k) a += b3[k] * wd1[k * 256 + t];
        b34[t] = a;
    }
}

// ---- pair MLP (2 layers) + fused decoder: grid 512, one WG per TWO rows
//      (w0=2bx, w0+1). j processed in TWO 64-row passes; hbuf[row][j][k]
//      swizzle: elem(j,k) at j*256 + ((k>>3 ^ (j&31))<<3) + (k&7), row 1 at
//      +16384 shorts. Wave wv owns n-slice n0=wv*64 (tn=2) for BOTH rows as
//      tj=2 tiles of 32x32x16 -> 16 MFMA per k-step. af ring-4 shared.
__global__ __launch_bounds__(256, 2) void pair_kernel(
        const float* __restrict__ ea, const float* __restrict__ eb,
        const unsigned short* __restrict__ wt,
        const float* __restrict__ b1, const float* __restrict__ b2,
        const float* __restrict__ W34, const float* __restrict__ b34,
        const float* __restrict__ wd2, const float* __restrict__ bd2,
        float* __restrict__ out) {
    __shared__ __align__(16) unsigned short hbuf[2 * 64 * 256];   // 64 KB
    __shared__ float ms[2][HID];   // pooled accumulator per row

    const int bx = blockIdx.x;
    const int w0 = bx * 2, b = w0 >> 7;
    const int t = threadIdx.x, wv = t >> 6, lane = t & 63;
    const int l31 = lane & 31, h5 = lane >> 5;
    const int n0 = wv * 64;

    const unsigned short* aptr = wt + lane * 8;   // + ((l*8 + wv*2+tn)*16 + kb)*512

    short8 af[4][2], bfr[2][2][2];   // af[ring][tn], bfr[buf][row][tj]
    float16v acc[2][2][2];           // [row][tn][tj]

#pragma unroll 1
    for (int pass = 0; pass < 2; ++pass) {
        // ring-4 preload: steps g = 0,1,2 of layer 0 (latency hides under preamble)
#pragma unroll
        for (int pg = 0; pg < 3; ++pg) {
            af[pg][0] = *(const short8*)(aptr + ((wv * 2 + 0) * 16 + pg) * 512);
            af[pg][1] = *(const short8*)(aptr + ((wv * 2 + 1) * 16 + pg) * 512);
        }

        // preamble: h0[r][j][k] = relu(ea[w0+r][k] + eb[b*128 + pass*64 + j][k])
        // wave fills rows j = wv*16 .. wv*16+15 for BOTH row-buffers;
        // eb load shared across the two rows.
        {
            const float4v va0 = *(const float4v*)(ea + w0 * 256 + lane * 4);
            const float4v va1 = *(const float4v*)(ea + (w0 + 1) * 256 + lane * 4);
            const float* ebbase = eb + (b * NOBJ + pass * 64) * 256;
            const int c = lane >> 1, sub = (lane & 1) * 4;
#pragma unroll 4
            for (int jj = 0; jj < 16; ++jj) {
                const int j = wv * 16 + jj;
                float4v vb = *(const float4v*)(ebbase + j * 256 + lane * 4);
                int addr = j * 256 + ((c ^ (j & 31)) << 3) + sub;
                *(uint2v*)(hbuf + addr) = (uint2v){
                    pack2(relu(va0[0] + vb[0]), relu(va0[1] + vb[1])),
                    pack2(relu(va0[2] + vb[2]), relu(va0[3] + vb[3]))};
                *(uint2v*)(hbuf + 16384 + addr) = (uint2v){
                    pack2(relu(va1[0] + vb[0]), relu(va1[1] + vb[1])),
                    pack2(relu(va1[2] + vb[2]), relu(va1[3] + vb[3]))};
            }
        }
        lds_barrier();

        int jb[2];
#pragma unroll
        for (int tj = 0; tj < 2; ++tj) jb[tj] = (tj * 32 + l31) * 256;
#pragma unroll
        for (int r = 0; r < 2; ++r)
#pragma unroll
            for (int tj = 0; tj < 2; ++tj)
                bfr[0][r][tj] = *(const short8*)(hbuf + r * 16384 + jb[tj] + ((h5 ^ l31) << 3));

#pragma unroll
        for (int l = 0; l < 2; ++l) {
            const float* bias = (l == 0) ? b1 : b2;
#pragma unroll
            for (int tn = 0; tn < 2; ++tn)
#pragma unroll
                for (int q = 0; q < 4; ++q) {
                    float4v bv = *(const float4v*)(bias + n0 + tn * 32 + q * 8 + h5 * 4);
#pragma unroll
                    for (int i = 0; i < 4; ++i)
#pragma unroll
                        for (int r = 0; r < 2; ++r)
#pragma unroll
                            for (int tj = 0; tj < 2; ++tj)
                                acc[r][tn][tj][q * 4 + i] = bv[i];
                }
#pragma unroll
            for (int kb = 0; kb < 16; ++kb) {
                const int g = l * 16 + kb, gp = g + 3;
                if (gp < 32) {   // ring-4: prefetch 3 steps ahead (crosses layers)
                    const int lp = gp >> 4, kp = gp & 15;
                    af[gp & 3][0] = *(const short8*)(aptr + ((lp * 8 + wv * 2 + 0) * 16 + kp) * 512);
                    af[gp & 3][1] = *(const short8*)(aptr + ((lp * 8 + wv * 2 + 1) * 16 + kp) * 512);
                }
                if (kb < 15) {   // prefetch next step's B from LDS (both rows)
                    const int off = ((((kb + 1) * 2 + h5) ^ l31) << 3);
#pragma unroll
                    for (int r = 0; r < 2; ++r)
#pragma unroll
                        for (int tj = 0; tj < 2; ++tj)
                            bfr[(kb + 1) & 1][r][tj] =
                                *(const short8*)(hbuf + r * 16384 + jb[tj] + off);
                }
#pragma unroll
                for (int tn = 0; tn < 2; ++tn)
#pragma unroll
                    for (int r = 0; r < 2; ++r)
#pragma unroll
                        for (int tj = 0; tj < 2; ++tj)
                            acc[r][tn][tj] = __builtin_amdgcn_mfma_f32_32x32x16_bf16(
                                af[g & 3][tn], bfr[kb & 1][r][tj], acc[r][tn][tj], 0, 0, 0);
            }
            lds_barrier();   // hbuf reads of layer l done

            if (l == 0) {
                // writeback h1 (relu, bf16) into swizzled layout, both rows
#pragma unroll
                for (int tn = 0; tn < 2; ++tn)
#pragma unroll
                    for (int q = 0; q < 4; ++q) {
                        const int nb_ = n0 + tn * 32 + 8 * q + 4 * h5;
                        const int cn = nb_ >> 3, sub = nb_ & 7;
#pragma unroll
                        for (int r = 0; r < 2; ++r)
#pragma unroll
                            for (int tj = 0; tj < 2; ++tj) {
                                const int j = tj * 32 + l31;
                                int addr = r * 16384 + j * 256 + ((cn ^ l31) << 3) + sub;
                                *(uint2v*)(hbuf + addr) = (uint2v){
                                    pack2(relu(acc[r][tn][tj][q * 4]), relu(acc[r][tn][tj][q * 4 + 1])),
                                    pack2(relu(acc[r][tn][tj][q * 4 + 2]), relu(acc[r][tn][tj][q * 4 + 3]))};
                            }
                    }
                lds_barrier();
#pragma unroll
                for (int r = 0; r < 2; ++r)
#pragma unroll
                    for (int tj = 0; tj < 2; ++tj)
                        bfr[0][r][tj] = *(const short8*)(hbuf + r * 16384 + jb[tj] + ((h5 ^ l31) << 3));
            }
        }

        // partial pooled sum over this pass's 64 j rows, both rows:
        // col j = l31, row n = n0 + tn*32 + (ri&3) + 8*(ri>>2) + 4*h5
#pragma unroll
        for (int r = 0; r < 2; ++r)
#pragma unroll
            for (int tn = 0; tn < 2; ++tn)
#pragma unroll
                for (int ri = 0; ri < 16; ++ri) {
                    float s = relu(acc[r][tn][0][ri]) + relu(acc[r][tn][1][ri]);
                    s += __shfl_xor(s, 1);
                    s += __shfl_xor(s, 2);
                    s += __shfl_xor(s, 4);
                    s += __shfl_xor(s, 8);
                    s += __shfl_xor(s, 16);
                    if (l31 == 0) {
                        const int n = n0 + tn * 32 + (ri & 3) + 8 * (ri >> 2) + 4 * h5;
                        if (pass == 0) ms[r][n] = s;
                        else           ms[r][n] = (ms[r][n] + s) * 0.0078125f;   // /128
                    }
                }
    }
    __syncthreads();

    // ---- epilogue (per row): t1 = relu(m2@W34 + b34); out = t1@wd2 + bd2
    // fs aliases hbuf (all h reads done): p1[0..1024) | t1[1024..1280) | p2[1280..1536)
    float* fs = (float*)hbuf;
#pragma unroll 1
    for (int rr = 0; rr < 2; ++rr) {
        {   // stage 1: m2 @ W34, 4-way k-split (wave wv covers k in [wv*64, wv*64+64))
            float p0 = 0.f, p1 = 0.f, p2 = 0.f, p3 = 0.f;
            const float* wp = W34 + (wv * 64) * 256 + lane;
#pragma unroll 8
            for (int kk = 0; kk < 64; ++kk) {
                float mv = ms[rr][wv * 64 + kk];
                p0 += mv * wp[kk * 256];
                p1 += mv * wp[kk * 256 + 64];
                p2 += mv * wp[kk * 256 + 128];
                p3 += mv * wp[kk * 256 + 192];
            }
            fs[wv * 256 + lane]       = p0;
            fs[wv * 256 + 64 + lane]  = p1;
            fs[wv * 256 + 128 + lane] = p2;
            fs[wv * 256 + 192 + lane] = p3;
        }
        __syncthreads();
        fs[1024 + t] = relu(fs[t] + fs[256 + t] + fs[512 + t] + fs[768 + t] + b34[t]);
        __syncthreads();
        {   // stage 2: t1 @ wd2 (wave wv covers k in [wv*64, wv*64+64), lane = output o)
            float p = 0.f;
            const float* w2p = wd2 + (wv * 64) * 64 + lane;
#pragma unroll 8
            for (int kk = 0; kk < 64; ++kk) p += fs[1024 + wv * 64 + kk] * w2p[kk * 64];
            fs[1280 + wv * 64 + lane] = p;
        }
        __syncthreads();
        if (t < 64)
            out[(w0 + rr) * 64 + t] = fs[1280 + t] + fs[1344 + t] + fs[1408 + t]
                                    + fs[1472 + t] + bd2[t];
        __syncthreads();   // fs reused by next row
    }
}

extern "C" void kernel_launch(void* const* d_in, const int* in_sizes, int n_in,
                              void* d_out, int out_size, void* d_ws, size_t ws_size,
                              hipStream_t stream) {
    const float* x0    = (const float*)d_in[0];
    const float* x1    = (const float*)d_in[1];
    const float* x2    = (const float*)d_in[2];
    const float* w_enc = (const float*)d_in[3];
    const float* b_enc = (const float*)d_in[4];
    const float* w1    = (const float*)d_in[5];
    const float* b1    = (const float*)d_in[6];
    const float* w2    = (const float*)d_in[7];
    const float* b2    = (const float*)d_in[8];
    const float* w3    = (const float*)d_in[9];
    const float* b3    = (const float*)d_in[10];
    const float* wd1   = (const float*)d_in[11];
    const float* bd1   = (const float*)d_in[12];
    const float* wd2   = (const float*)d_in[13];
    const float* bd2   = (const float*)d_in[14];
    float* out = (float*)d_out;

    // workspace: wfrag 256KB (in 384KB slot) | ea 1MB | eb 1MB | W34 256KB | b34 1KB
    unsigned short* wt = (unsigned short*)d_ws;
    float* ea  = (float*)((char*)d_ws + 3 * 65536 * sizeof(unsigned short));
    float* eb  = ea + NROW * HID;
    float* W34 = eb + NROW * HID;
    float* b34 = W34 + 256 * 256;

    setup_kernel<<<785, 256, 0, stream>>>(x0, x1, x2, w_enc, b_enc, w1, w2,
                                          w3, b3, wd1, bd1, wt, ea, eb, W34, b34);
    pair_kernel<<<NROW / 2, 256, 0, stream>>>(ea, eb, wt, b1, b2, W34, b34, wd2, bd2, out);
}

// Round 5
// 167.133 us; speedup vs baseline: 1.5290x; 1.1674x over previous
//
#include <hip/hip_runtime.h>
#include <stdint.h>

// B=8, OBJ=128, INP=64, HID=256, D=192.
// R26: decoder split. R22-R25 established: any deviation from R20/R21's
// register shape (100 arch + 128 AGPR at launch_bounds(256,2)) spills
// (WRITE_SIZE 270/64/225/49 MB). So the pair loop is byte-identical to R21
// (65.8us, ring-4). Change: the epilogue GEMV (every block streaming all
// 256KB of W34 from L2 = 256MB aggregate + 4 drained barriers) moves to a
// third kernel that amortizes W34 over 8 rows/block (32MB L2 traffic).
// pair_kernel now ends at the pool and stores m2 (fp32, coalesced) to a
// 1MB workspace buffer. Decoder stays fp32 for precision.

#define HID 256
#define NOBJ 128
#define NROW 1024   // B*OBJ

typedef __attribute__((ext_vector_type(8))) short short8;
typedef __attribute__((ext_vector_type(4))) float float4v;
typedef __attribute__((ext_vector_type(16))) float float16v;
typedef __attribute__((ext_vector_type(2))) unsigned int uint2v;

__device__ __forceinline__ unsigned int f2bf_u(float f) {
    unsigned int u = __builtin_bit_cast(unsigned int, f);
    u += 0x7fffu + ((u >> 16) & 1u);   // RNE
    return u >> 16;
}
__device__ __forceinline__ unsigned int pack2(float a, float b) {
    return f2bf_u(a) | (f2bf_u(b) << 16);
}
__device__ __forceinline__ float relu(float v) { return v > 0.f ? v : 0.f; }

// LDS-only barrier: leaves global-load (vmcnt) prefetches in flight.
__device__ __forceinline__ void lds_barrier() {
    asm volatile("s_waitcnt lgkmcnt(0)\n\ts_barrier" ::: "memory");
}

// ---- setup:
//  blocks [0,16): fragment-major pack of w1,w2 (layer m = bx>>3, n-tile tau = bx&7)
//  blocks [16,528): encoder, 2 rows each (fold b_enc into ea)
//  blocks [528,784): W34 row m = bx-528:  W34[m][o] = sum_k w3[m][k]*wd1[k][o]
//  block  784:       b34[o] = sum_k b3[k]*wd1[k][o] + bd1[o]
__global__ void setup_kernel(const float* __restrict__ x0, const float* __restrict__ x1,
                             const float* __restrict__ x2, const float* __restrict__ w_enc,
                             const float* __restrict__ b_enc,
                             const float* __restrict__ w1, const float* __restrict__ w2,
                             const float* __restrict__ w3, const float* __restrict__ b3,
                             const float* __restrict__ wd1, const float* __restrict__ bd1,
                             unsigned short* __restrict__ wt,
                             float* __restrict__ ea, float* __restrict__ eb,
                             float* __restrict__ W34, float* __restrict__ b34) {
    const int bx = blockIdx.x, t = threadIdx.x;
    __shared__ float lw[256][33];          // [k][n-within-tile]
    __shared__ float xs[2][192];
    if (bx < 16) {
        const int m = bx >> 3, tau = bx & 7;
        const float* w = (m == 0) ? w1 : w2;
        const int n = t & 31, kk = t >> 5;     // 8 k-rows per pass
#pragma unroll
        for (int rep = 0; rep < 32; ++rep) {
            int k = rep * 8 + kk;
            lw[k][n] = w[k * 256 + tau * 32 + n];   // coalesced 128B segments
        }
        __syncthreads();
        unsigned short* outp = wt + (m * 8 + tau) * 8192;
        const int lane = t & 63, wq = t >> 6;
        const int h5 = lane >> 5, l31n = lane & 31;
#pragma unroll
        for (int rep = 0; rep < 4; ++rep) {
            const int kb = wq * 4 + rep;
            short8 v;
#pragma unroll
            for (int e = 0; e < 8; ++e)
                v[e] = (short)f2bf_u(lw[kb * 16 + h5 * 8 + e][l31n]);
            *(short8*)(outp + kb * 512 + lane * 8) = v;   // wave-contiguous 1KB
        }
        return;
    }
    if (bx < 528) {
        const int e = bx - 16;                 // 512 groups x 2 rows
        for (int idx = t; idx < 384; idx += 256) {
            int r = idx / 192, d = idx % 192;
            int row = e * 2 + r;
            float v = (d < 64) ? x0[row * 64 + d]
                    : (d < 128) ? x1[row * 64 + d - 64]
                    : x2[row * 64 + d - 128];
            xs[r][d] = v;
        }
        __syncthreads();
        float aA[2] = {0.f, 0.f}, aB[2] = {0.f, 0.f};
#pragma unroll 16
        for (int d = 0; d < 192; ++d) {
            float wa = w_enc[d * 256 + t];
            float wb = w_enc[(192 + d) * 256 + t];
#pragma unroll
            for (int r = 0; r < 2; ++r) { aA[r] += xs[r][d] * wa; aB[r] += xs[r][d] * wb; }
        }
        float be = b_enc[t];
#pragma unroll
        for (int r = 0; r < 2; ++r) {
            ea[(e * 2 + r) * 256 + t] = aA[r] + be;
            eb[(e * 2 + r) * 256 + t] = aB[r];
        }
        return;
    }
    if (bx < 784) {
        const int m = bx - 528;
        float a = 0.f;
#pragma unroll 8
        for (int k = 0; k < 256; ++k) a += w3[m * 256 + k] * wd1[k * 256 + t];
        W34[m * 256 + t] = a;
        return;
    }
    {   // b34
        float a = bd1[t];
#pragma unroll 8
        for (int k = 0; k < 256; ++k) a += b3[k] * wd1[k * 256 + t];
        b34[t] = a;
    }
}

// ---- pair MLP (2 layers) + pool: grid 1024, one WG per (b,i).
//      128 j-rows, 64 KB LDS h, swizzle: elem(j,k) at
//      j*256 + ((k>>3 ^ (j&31))<<3) + (k&7). Wave wv owns n-quarter n0=wv*64
//      as tn=2 x tj=4 tiles of 32x32x16. af ring-4 (prefetch distance 3).
//      Ends at the pool: m2 row (256 fp32) stored coalesced to msg.
__global__ __launch_bounds__(256, 2) void pair_kernel(
        const float* __restrict__ ea, const float* __restrict__ eb,
        const unsigned short* __restrict__ wt,
        const float* __restrict__ b1, const float* __restrict__ b2,
        float* __restrict__ msg) {
    __shared__ __align__(16) unsigned short hbuf[128 * 256];   // 64 KB
    __shared__ float ms[HID];

    const int w = blockIdx.x, b = w >> 7;
    const int t = threadIdx.x, wv = t >> 6, lane = t & 63;
    const int l31 = lane & 31, h5 = lane >> 5;
    const int n0 = wv * 64;

    const unsigned short* aptr = wt + lane * 8;   // + ((l*8 + wv*2+tn)*16 + kb)*512

    short8 af[4][2], bfr[2][4];
    // ring-4 preload: steps g = 0,1,2 of layer 0
#pragma unroll
    for (int pg = 0; pg < 3; ++pg) {
        af[pg][0] = *(const short8*)(aptr + ((wv * 2 + 0) * 16 + pg) * 512);
        af[pg][1] = *(const short8*)(aptr + ((wv * 2 + 1) * 16 + pg) * 512);
    }

    // preamble: h0[j][k] = relu(ea[w][k] + eb[b*128+j][k]); wave fills j=wv*32..+31
    {
        const float4v va = *(const float4v*)(ea + w * 256 + lane * 4);
        const float* ebbase = eb + (b * NOBJ) * 256;
        const int c = lane >> 1, sub = (lane & 1) * 4;
#pragma unroll 4
        for (int jj = 0; jj < 32; ++jj) {
            const int j = wv * 32 + jj;
            float4v vb = *(const float4v*)(ebbase + j * 256 + lane * 4);
            int addr = j * 256 + ((c ^ (j & 31)) << 3) + sub;
            *(uint2v*)(hbuf + addr) = (uint2v){
                pack2(relu(va[0] + vb[0]), relu(va[1] + vb[1])),
                pack2(relu(va[2] + vb[2]), relu(va[3] + vb[3]))};
        }
    }
    lds_barrier();

    int jb[4];
#pragma unroll
    for (int tj = 0; tj < 4; ++tj) jb[tj] = (tj * 32 + l31) * 256;
#pragma unroll
    for (int tj = 0; tj < 4; ++tj)
        bfr[0][tj] = *(const short8*)(hbuf + jb[tj] + ((h5 ^ l31) << 3));

    float16v acc[2][4];   // [tn][tj]

#pragma unroll
    for (int l = 0; l < 2; ++l) {
        const float* bias = (l == 0) ? b1 : b2;
#pragma unroll
        for (int tn = 0; tn < 2; ++tn)
#pragma unroll
            for (int q = 0; q < 4; ++q) {
                float4v bv = *(const float4v*)(bias + n0 + tn * 32 + q * 8 + h5 * 4);
#pragma unroll
                for (int i = 0; i < 4; ++i)
#pragma unroll
                    for (int tj = 0; tj < 4; ++tj)
                        acc[tn][tj][q * 4 + i] = bv[i];
            }
#pragma unroll
        for (int kb = 0; kb < 16; ++kb) {
            const int g = l * 16 + kb, gp = g + 3;
            if (gp < 32) {   // prefetch 3 steps ahead (crosses the layer boundary)
                const int lp = gp >> 4, kp = gp & 15;
                af[gp & 3][0] = *(const short8*)(aptr + ((lp * 8 + wv * 2 + 0) * 16 + kp) * 512);
                af[gp & 3][1] = *(const short8*)(aptr + ((lp * 8 + wv * 2 + 1) * 16 + kp) * 512);
            }
            if (kb < 15) {   // prefetch next step's B from LDS
                const int off = ((((kb + 1) * 2 + h5) ^ l31) << 3);
#pragma unroll
                for (int tj = 0; tj < 4; ++tj)
                    bfr[(kb + 1) & 1][tj] = *(const short8*)(hbuf + jb[tj] + off);
            }
#pragma unroll
            for (int tn = 0; tn < 2; ++tn)
#pragma unroll
                for (int tj = 0; tj < 4; ++tj)
                    acc[tn][tj] = __builtin_amdgcn_mfma_f32_32x32x16_bf16(
                        af[g & 3][tn], bfr[kb & 1][tj], acc[tn][tj], 0, 0, 0);
        }

        if (l == 0) {
            lds_barrier();   // hbuf reads of layer 0 done
            // writeback h1 (relu, bf16) into swizzled layout
#pragma unroll
            for (int tn = 0; tn < 2; ++tn)
#pragma unroll
                for (int q = 0; q < 4; ++q) {
                    const int nb_ = n0 + tn * 32 + 8 * q + 4 * h5;
                    const int cn = nb_ >> 3, sub = nb_ & 7;
#pragma unroll
                    for (int tj = 0; tj < 4; ++tj) {
                        const int j = tj * 32 + l31;
                        int addr = j * 256 + ((cn ^ l31) << 3) + sub;
                        *(uint2v*)(hbuf + addr) = (uint2v){
                            pack2(relu(acc[tn][tj][q * 4]), relu(acc[tn][tj][q * 4 + 1])),
                            pack2(relu(acc[tn][tj][q * 4 + 2]), relu(acc[tn][tj][q * 4 + 3]))};
                    }
                }
            lds_barrier();
#pragma unroll
            for (int tj = 0; tj < 4; ++tj)
                bfr[0][tj] = *(const short8*)(hbuf + jb[tj] + ((h5 ^ l31) << 3));
        }
    }

    // ---- pool: m2[n] = mean_j relu(acc); gather in LDS, coalesced store
#pragma unroll
    for (int tn = 0; tn < 2; ++tn)
#pragma unroll
        for (int r = 0; r < 16; ++r) {
            float s = relu(acc[tn][0][r]) + relu(acc[tn][1][r])
                    + relu(acc[tn][2][r]) + relu(acc[tn][3][r]);
            s += __shfl_xor(s, 1);
            s += __shfl_xor(s, 2);
            s += __shfl_xor(s, 4);
            s += __shfl_xor(s, 8);
            s += __shfl_xor(s, 16);
            if (l31 == 0) {
                const int n = n0 + tn * 32 + (r & 3) + 8 * (r >> 2) + 4 * h5;
                ms[n] = s * 0.0078125f;   // /128
            }
        }
    __syncthreads();
    if (t < 64)
        *(float4v*)(msg + w * 256 + t * 4) = *(const float4v*)(ms + t * 4);
}

// ---- decoder: out = relu(m2@W34 + b34) @ wd2 + bd2, fp32.
//      grid 128, 8 rows per block: W34 streamed from L2 once per 8 rows
//      (32MB aggregate vs 256MB when fused per-row).
__global__ __launch_bounds__(256) void decoder_kernel(
        const float* __restrict__ msg, const float* __restrict__ W34,
        const float* __restrict__ b34, const float* __restrict__ wd2,
        const float* __restrict__ bd2, float* __restrict__ out) {
    __shared__ float ml[8][256];
    __shared__ float tl[8][256];
    const int bx = blockIdx.x, t = threadIdx.x;
    const int r0 = bx * 8;

#pragma unroll
    for (int r = 0; r < 8; ++r) ml[r][t] = msg[(r0 + r) * 256 + t];
    __syncthreads();

    // stage 1: t1[r][t] = relu(sum_k m2[r][k]*W34[k][t] + b34[t])
    {
        float a[8];
        const float bb = b34[t];
#pragma unroll
        for (int r = 0; r < 8; ++r) a[r] = bb;
#pragma unroll 8
        for (int k = 0; k < 256; ++k) {
            const float wv_ = W34[k * 256 + t];
#pragma unroll
            for (int r = 0; r < 8; ++r) a[r] += ml[r][k] * wv_;
        }
#pragma unroll
        for (int r = 0; r < 8; ++r) tl[r][t] = relu(a[r]);
    }
    __syncthreads();

    // stage 2: out[r][o] = sum_k t1[r][k]*wd2[k][o] + bd2[o]
    // thread t: o = t&63, rows 2*(t>>6), 2*(t>>6)+1
    {
        const int o = t & 63, rg = t >> 6;
        float a0 = bd2[o], a1 = a0;
#pragma unroll 8
        for (int k = 0; k < 256; ++k) {
            const float wv_ = wd2[k * 64 + o];
            a0 += tl[2 * rg][k] * wv_;
            a1 += tl[2 * rg + 1][k] * wv_;
        }
        out[(r0 + 2 * rg) * 64 + o]     = a0;
        out[(r0 + 2 * rg + 1) * 64 + o] = a1;
    }
}

extern "C" void kernel_launch(void* const* d_in, const int* in_sizes, int n_in,
                              void* d_out, int out_size, void* d_ws, size_t ws_size,
                              hipStream_t stream) {
    const float* x0    = (const float*)d_in[0];
    const float* x1    = (const float*)d_in[1];
    const float* x2    = (const float*)d_in[2];
    const float* w_enc = (const float*)d_in[3];
    const float* b_enc = (const float*)d_in[4];
    const float* w1    = (const float*)d_in[5];
    const float* b1    = (const float*)d_in[6];
    const float* w2    = (const float*)d_in[7];
    const float* b2    = (const float*)d_in[8];
    const float* w3    = (const float*)d_in[9];
    const float* b3    = (const float*)d_in[10];
    const float* wd1   = (const float*)d_in[11];
    const float* bd1   = (const float*)d_in[12];
    const float* wd2   = (const float*)d_in[13];
    const float* bd2   = (const float*)d_in[14];
    float* out = (float*)d_out;

    // workspace: wfrag 256KB (384KB slot) | ea 1MB | eb 1MB | W34 256KB |
    //            b34 1KB | msg 1MB
    unsigned short* wt = (unsigned short*)d_ws;
    float* ea  = (float*)((char*)d_ws + 3 * 65536 * sizeof(unsigned short));
    float* eb  = ea + NROW * HID;
    float* W34 = eb + NROW * HID;
    float* b34 = W34 + 256 * 256;
    float* msg = b34 + 256;

    setup_kernel<<<785, 256, 0, stream>>>(x0, x1, x2, w_enc, b_enc, w1, w2,
                                          w3, b3, wd1, bd1, wt, ea, eb, W34, b34);
    pair_kernel<<<NROW, 256, 0, stream>>>(ea, eb, wt, b1, b2, msg);
    decoder_kernel<<<NROW / 8, 256, 0, stream>>>(msg, W34, b34, wd2, bd2, out);
}

// Round 6
// 154.475 us; speedup vs baseline: 1.6543x; 1.0819x over previous
//
#include <hip/hip_runtime.h>
#include <stdint.h>

// B=8, OBJ=128, INP=64, HID=256, D=192.
// R27: decoder v2. R26 proved the split (pair 65.8 -> 54.9us, no spill) but
// the decoder cost ~16-20us: grid 128 (half the CUs), 1 wave/SIMD, 8 loads
// in flight against ~600-900cyc first-touch latency on W34. v2: grid 256,
// 512 threads (2 waves/SIMD), 4 rows/block, 2-way k-split in both stages,
// unroll 16 -> ~8 pipelined load groups; LDS reduce for partials; fp32
// throughout. Floor ~3us (67MB L2 + 0.9us VALU). setup/pair byte-identical
// to R26. Decision rule: total >=162 => 3-kernel overhead theory wins,
// revert to fused epilogue next.

#define HID 256
#define NOBJ 128
#define NROW 1024   // B*OBJ

typedef __attribute__((ext_vector_type(8))) short short8;
typedef __attribute__((ext_vector_type(4))) float float4v;
typedef __attribute__((ext_vector_type(16))) float float16v;
typedef __attribute__((ext_vector_type(2))) unsigned int uint2v;

__device__ __forceinline__ unsigned int f2bf_u(float f) {
    unsigned int u = __builtin_bit_cast(unsigned int, f);
    u += 0x7fffu + ((u >> 16) & 1u);   // RNE
    return u >> 16;
}
__device__ __forceinline__ unsigned int pack2(float a, float b) {
    return f2bf_u(a) | (f2bf_u(b) << 16);
}
__device__ __forceinline__ float relu(float v) { return v > 0.f ? v : 0.f; }

// LDS-only barrier: leaves global-load (vmcnt) prefetches in flight.
__device__ __forceinline__ void lds_barrier() {
    asm volatile("s_waitcnt lgkmcnt(0)\n\ts_barrier" ::: "memory");
}

// ---- setup:
//  blocks [0,16): fragment-major pack of w1,w2 (layer m = bx>>3, n-tile tau = bx&7)
//  blocks [16,528): encoder, 2 rows each (fold b_enc into ea)
//  blocks [528,784): W34 row m = bx-528:  W34[m][o] = sum_k w3[m][k]*wd1[k][o]
//  block  784:       b34[o] = sum_k b3[k]*wd1[k][o] + bd1[o]
__global__ void setup_kernel(const float* __restrict__ x0, const float* __restrict__ x1,
                             const float* __restrict__ x2, const float* __restrict__ w_enc,
                             const float* __restrict__ b_enc,
                             const float* __restrict__ w1, const float* __restrict__ w2,
                             const float* __restrict__ w3, const float* __restrict__ b3,
                             const float* __restrict__ wd1, const float* __restrict__ bd1,
                             unsigned short* __restrict__ wt,
                             float* __restrict__ ea, float* __restrict__ eb,
                             float* __restrict__ W34, float* __restrict__ b34) {
    const int bx = blockIdx.x, t = threadIdx.x;
    __shared__ float lw[256][33];          // [k][n-within-tile]
    __shared__ float xs[2][192];
    if (bx < 16) {
        const int m = bx >> 3, tau = bx & 7;
        const float* w = (m == 0) ? w1 : w2;
        const int n = t & 31, kk = t >> 5;     // 8 k-rows per pass
#pragma unroll
        for (int rep = 0; rep < 32; ++rep) {
            int k = rep * 8 + kk;
            lw[k][n] = w[k * 256 + tau * 32 + n];   // coalesced 128B segments
        }
        __syncthreads();
        unsigned short* outp = wt + (m * 8 + tau) * 8192;
        const int lane = t & 63, wq = t >> 6;
        const int h5 = lane >> 5, l31n = lane & 31;
#pragma unroll
        for (int rep = 0; rep < 4; ++rep) {
            const int kb = wq * 4 + rep;
            short8 v;
#pragma unroll
            for (int e = 0; e < 8; ++e)
                v[e] = (short)f2bf_u(lw[kb * 16 + h5 * 8 + e][l31n]);
            *(short8*)(outp + kb * 512 + lane * 8) = v;   // wave-contiguous 1KB
        }
        return;
    }
    if (bx < 528) {
        const int e = bx - 16;                 // 512 groups x 2 rows
        for (int idx = t; idx < 384; idx += 256) {
            int r = idx / 192, d = idx % 192;
            int row = e * 2 + r;
            float v = (d < 64) ? x0[row * 64 + d]
                    : (d < 128) ? x1[row * 64 + d - 64]
                    : x2[row * 64 + d - 128];
            xs[r][d] = v;
        }
        __syncthreads();
        float aA[2] = {0.f, 0.f}, aB[2] = {0.f, 0.f};
#pragma unroll 16
        for (int d = 0; d < 192; ++d) {
            float wa = w_enc[d * 256 + t];
            float wb = w_enc[(192 + d) * 256 + t];
#pragma unroll
            for (int r = 0; r < 2; ++r) { aA[r] += xs[r][d] * wa; aB[r] += xs[r][d] * wb; }
        }
        float be = b_enc[t];
#pragma unroll
        for (int r = 0; r < 2; ++r) {
            ea[(e * 2 + r) * 256 + t] = aA[r] + be;
            eb[(e * 2 + r) * 256 + t] = aB[r];
        }
        return;
    }
    if (bx < 784) {
        const int m = bx - 528;
        float a = 0.f;
#pragma unroll 8
        for (int k = 0; k < 256; ++k) a += w3[m * 256 + k] * wd1[k * 256 + t];
        W34[m * 256 + t] = a;
        return;
    }
    {   // b34
        float a = bd1[t];
#pragma unroll 8
        for (int k = 0; k < 256; ++k) a += b3[k] * wd1[k * 256 + t];
        b34[t] = a;
    }
}

// ---- pair MLP (2 layers) + pool: grid 1024, one WG per (b,i).
//      128 j-rows, 64 KB LDS h, swizzle: elem(j,k) at
//      j*256 + ((k>>3 ^ (j&31))<<3) + (k&7). Wave wv owns n-quarter n0=wv*64
//      as tn=2 x tj=4 tiles of 32x32x16. af ring-4 (prefetch distance 3).
//      Ends at the pool: m2 row (256 fp32) stored coalesced to msg.
__global__ __launch_bounds__(256, 2) void pair_kernel(
        const float* __restrict__ ea, const float* __restrict__ eb,
        const unsigned short* __restrict__ wt,
        const float* __restrict__ b1, const float* __restrict__ b2,
        float* __restrict__ msg) {
    __shared__ __align__(16) unsigned short hbuf[128 * 256];   // 64 KB
    __shared__ float ms[HID];

    const int w = blockIdx.x, b = w >> 7;
    const int t = threadIdx.x, wv = t >> 6, lane = t & 63;
    const int l31 = lane & 31, h5 = lane >> 5;
    const int n0 = wv * 64;

    const unsigned short* aptr = wt + lane * 8;   // + ((l*8 + wv*2+tn)*16 + kb)*512

    short8 af[4][2], bfr[2][4];
    // ring-4 preload: steps g = 0,1,2 of layer 0
#pragma unroll
    for (int pg = 0; pg < 3; ++pg) {
        af[pg][0] = *(const short8*)(aptr + ((wv * 2 + 0) * 16 + pg) * 512);
        af[pg][1] = *(const short8*)(aptr + ((wv * 2 + 1) * 16 + pg) * 512);
    }

    // preamble: h0[j][k] = relu(ea[w][k] + eb[b*128+j][k]); wave fills j=wv*32..+31
    {
        const float4v va = *(const float4v*)(ea + w * 256 + lane * 4);
        const float* ebbase = eb + (b * NOBJ) * 256;
        const int c = lane >> 1, sub = (lane & 1) * 4;
#pragma unroll 4
        for (int jj = 0; jj < 32; ++jj) {
            const int j = wv * 32 + jj;
            float4v vb = *(const float4v*)(ebbase + j * 256 + lane * 4);
            int addr = j * 256 + ((c ^ (j & 31)) << 3) + sub;
            *(uint2v*)(hbuf + addr) = (uint2v){
                pack2(relu(va[0] + vb[0]), relu(va[1] + vb[1])),
                pack2(relu(va[2] + vb[2]), relu(va[3] + vb[3]))};
        }
    }
    lds_barrier();

    int jb[4];
#pragma unroll
    for (int tj = 0; tj < 4; ++tj) jb[tj] = (tj * 32 + l31) * 256;
#pragma unroll
    for (int tj = 0; tj < 4; ++tj)
        bfr[0][tj] = *(const short8*)(hbuf + jb[tj] + ((h5 ^ l31) << 3));

    float16v acc[2][4];   // [tn][tj]

#pragma unroll
    for (int l = 0; l < 2; ++l) {
        const float* bias = (l == 0) ? b1 : b2;
#pragma unroll
        for (int tn = 0; tn < 2; ++tn)
#pragma unroll
            for (int q = 0; q < 4; ++q) {
                float4v bv = *(const float4v*)(bias + n0 + tn * 32 + q * 8 + h5 * 4);
#pragma unroll
                for (int i = 0; i < 4; ++i)
#pragma unroll
                    for (int tj = 0; tj < 4; ++tj)
                        acc[tn][tj][q * 4 + i] = bv[i];
            }
#pragma unroll
        for (int kb = 0; kb < 16; ++kb) {
            const int g = l * 16 + kb, gp = g + 3;
            if (gp < 32) {   // prefetch 3 steps ahead (crosses the layer boundary)
                const int lp = gp >> 4, kp = gp & 15;
                af[gp & 3][0] = *(const short8*)(aptr + ((lp * 8 + wv * 2 + 0) * 16 + kp) * 512);
                af[gp & 3][1] = *(const short8*)(aptr + ((lp * 8 + wv * 2 + 1) * 16 + kp) * 512);
            }
            if (kb < 15) {   // prefetch next step's B from LDS
                const int off = ((((kb + 1) * 2 + h5) ^ l31) << 3);
#pragma unroll
                for (int tj = 0; tj < 4; ++tj)
                    bfr[(kb + 1) & 1][tj] = *(const short8*)(hbuf + jb[tj] + off);
            }
#pragma unroll
            for (int tn = 0; tn < 2; ++tn)
#pragma unroll
                for (int tj = 0; tj < 4; ++tj)
                    acc[tn][tj] = __builtin_amdgcn_mfma_f32_32x32x16_bf16(
                        af[g & 3][tn], bfr[kb & 1][tj], acc[tn][tj], 0, 0, 0);
        }

        if (l == 0) {
            lds_barrier();   // hbuf reads of layer 0 done
            // writeback h1 (relu, bf16) into swizzled layout
#pragma unroll
            for (int tn = 0; tn < 2; ++tn)
#pragma unroll
                for (int q = 0; q < 4; ++q) {
                    const int nb_ = n0 + tn * 32 + 8 * q + 4 * h5;
                    const int cn = nb_ >> 3, sub = nb_ & 7;
#pragma unroll
                    for (int tj = 0; tj < 4; ++tj) {
                        const int j = tj * 32 + l31;
                        int addr = j * 256 + ((cn ^ l31) << 3) + sub;
                        *(uint2v*)(hbuf + addr) = (uint2v){
                            pack2(relu(acc[tn][tj][q * 4]), relu(acc[tn][tj][q * 4 + 1])),
                            pack2(relu(acc[tn][tj][q * 4 + 2]), relu(acc[tn][tj][q * 4 + 3]))};
                    }
                }
            lds_barrier();
#pragma unroll
            for (int tj = 0; tj < 4; ++tj)
                bfr[0][tj] = *(const short8*)(hbuf + jb[tj] + ((h5 ^ l31) << 3));
        }
    }

    // ---- pool: m2[n] = mean_j relu(acc); gather in LDS, coalesced store
#pragma unroll
    for (int tn = 0; tn < 2; ++tn)
#pragma unroll
        for (int r = 0; r < 16; ++r) {
            float s = relu(acc[tn][0][r]) + relu(acc[tn][1][r])
                    + relu(acc[tn][2][r]) + relu(acc[tn][3][r]);
            s += __shfl_xor(s, 1);
            s += __shfl_xor(s, 2);
            s += __shfl_xor(s, 4);
            s += __shfl_xor(s, 8);
            s += __shfl_xor(s, 16);
            if (l31 == 0) {
                const int n = n0 + tn * 32 + (r & 3) + 8 * (r >> 2) + 4 * h5;
                ms[n] = s * 0.0078125f;   // /128
            }
        }
    __syncthreads();
    if (t < 64)
        *(float4v*)(msg + w * 256 + t * 4) = *(const float4v*)(ms + t * 4);
}

// ---- decoder v2: out = relu(m2@W34 + b34) @ wd2 + bd2, fp32.
//      grid 256 (every CU), 512 threads (2 waves/SIMD), 4 rows/block,
//      2-way k-split both stages, unroll 16 -> deep load pipeline.
__global__ __launch_bounds__(512) void decoder_kernel(
        const float* __restrict__ msg, const float* __restrict__ W34,
        const float* __restrict__ b34, const float* __restrict__ wd2,
        const float* __restrict__ bd2, float* __restrict__ out) {
    __shared__ float ml[4][256];        // m2 rows
    __shared__ float ps[2][4][256];     // stage1 partials [kh][r][n]
    __shared__ float tl[4][256];        // t1 rows
    __shared__ float p2[2][4][64];      // stage2 partials [kh][r][o]
    const int bx = blockIdx.x, t = threadIdx.x;
    const int r0 = bx * 4;

#pragma unroll
    for (int i = t; i < 1024; i += 512) ml[i >> 8][i & 255] = msg[r0 * 256 + i];
    __syncthreads();

    // stage 1: ps[kh][r][n] = sum_{k in kh-half} m2[r][k] * W34[k][n]
    {
        const int n = t & 255, kh = t >> 8;
        float a0 = 0.f, a1 = 0.f, a2 = 0.f, a3 = 0.f;
        const float* wp = W34 + (kh * 128) * 256 + n;
        const float* m0 = &ml[0][kh * 128];
        const float* m1 = &ml[1][kh * 128];
        const float* m2r = &ml[2][kh * 128];
        const float* m3 = &ml[3][kh * 128];
#pragma unroll 16
        for (int k = 0; k < 128; ++k) {
            const float wv_ = wp[k * 256];
            a0 += m0[k] * wv_;
            a1 += m1[k] * wv_;
            a2 += m2r[k] * wv_;
            a3 += m3[k] * wv_;
        }
        ps[kh][0][n] = a0; ps[kh][1][n] = a1; ps[kh][2][n] = a2; ps[kh][3][n] = a3;
    }
    __syncthreads();
#pragma unroll
    for (int i = t; i < 1024; i += 512) {
        const int r = i >> 8, nn = i & 255;
        tl[r][nn] = relu(ps[0][r][nn] + ps[1][r][nn] + b34[nn]);
    }
    __syncthreads();

    // stage 2: p2[kh][r][o] = sum_{k in kh-half} t1[r][k] * wd2[k][o]
    {
        const int o = t & 63, rr = (t >> 6) & 3, kh = t >> 8;
        float a = 0.f;
        const float* w2p = wd2 + (kh * 128) * 64 + o;
        const float* tp = &tl[rr][kh * 128];
#pragma unroll 16
        for (int k = 0; k < 128; ++k) a += tp[k] * w2p[k * 64];
        p2[kh][rr][o] = a;
    }
    __syncthreads();
    if (t < 256) {
        const int o = t & 63, r = t >> 6;
        out[(r0 + r) * 64 + o] = p2[0][r][o] + p2[1][r][o] + bd2[o];
    }
}

extern "C" void kernel_launch(void* const* d_in, const int* in_sizes, int n_in,
                              void* d_out, int out_size, void* d_ws, size_t ws_size,
                              hipStream_t stream) {
    const float* x0    = (const float*)d_in[0];
    const float* x1    = (const float*)d_in[1];
    const float* x2    = (const float*)d_in[2];
    const float* w_enc = (const float*)d_in[3];
    const float* b_enc = (const float*)d_in[4];
    const float* w1    = (const float*)d_in[5];
    const float* b1    = (const float*)d_in[6];
    const float* w2    = (const float*)d_in[7];
    const float* b2    = (const float*)d_in[8];
    const float* w3    = (const float*)d_in[9];
    const float* b3    = (const float*)d_in[10];
    const float* wd1   = (const float*)d_in[11];
    const float* bd1   = (const float*)d_in[12];
    const float* wd2   = (const float*)d_in[13];
    const float* bd2   = (const float*)d_in[14];
    float* out = (float*)d_out;

    // workspace: wfrag 256KB (384KB slot) | ea 1MB | eb 1MB | W34 256KB |
    //            b34 1KB | msg 1MB
    unsigned short* wt = (unsigned short*)d_ws;
    float* ea  = (float*)((char*)d_ws + 3 * 65536 * sizeof(unsigned short));
    float* eb  = ea + NROW * HID;
    float* W34 = eb + NROW * HID;
    float* b34 = W34 + 256 * 256;
    float* msg = b34 + 256;

    setup_kernel<<<785, 256, 0, stream>>>(x0, x1, x2, w_enc, b_enc, w1, w2,
                                          w3, b3, wd1, bd1, wt, ea, eb, W34, b34);
    pair_kernel<<<NROW, 256, 0, stream>>>(ea, eb, wt, b1, b2, msg);
    decoder_kernel<<<NROW / 4, 512, 0, stream>>>(msg, W34, b34, wd2, bd2, out);
}